// Round 4
// baseline (130.453 us; speedup 1.0000x reference)
//
#include <hip/hip_runtime.h>
#include <stdint.h>

#define N_PTS 256

typedef unsigned long long ull;
typedef float v2f __attribute__((ext_vector_type(2)));

__device__ __forceinline__ unsigned umin2(unsigned a, unsigned b) { return a < b ? a : b; }

template<int CTRL>
__device__ __forceinline__ float dpp_min1(float x) {
    int xi = __float_as_int(x);
    int yi = __builtin_amdgcn_update_dpp(xi, xi, CTRL, 0xf, 0xf, false);
    return fminf(x, __int_as_float(yi));
}

// One greedy round: resolve target (tjx,tjy) against the live candidate set.
// Candidates: lane L owns k = s*64+L, coords packed (x,y) per slot (v_pk math).
// Used candidates have x poisoned to NaN -> distance NaN -> skipped by
// v_min_f32 (minNum) and by uint-compare (NaN bits sort above +inf).
__device__ __forceinline__ void round_one(
    float tjx, float tjy, int lane, float& acc,
    v2f& p0, v2f& p1, v2f& p2, v2f& p3)
{
    #pragma clang fp contract(off)
    const unsigned BIG_U = __float_as_uint(66049.0f);  // 257^2 sentinel bits

    v2f t; t.x = tjx; t.y = tjy;
    // packed distances: pk_sub, pk_mul, cross add (separate mul/add rounding
    // == fp32 numpy reference -> identical greedy trajectory)
    v2f q0 = t - p0, q1 = t - p1, q2 = t - p2, q3 = t - p3;
    v2f s0 = q0 * q0, s1 = q1 * q1, s2 = q2 * q2, s3 = q3 * q3;
    float d0 = s0.x + s0.y;
    float d1 = s1.x + s1.y;
    float d2 = s2.x + s2.y;
    float d3 = s3.x + s3.y;

    // per-lane min of 4 (v_min3 + v_min), then 4 DPP row_shr stages ->
    // per-row minima at lanes 15/31/47/63
    float m = fminf(fminf(fminf(d0, d1), d2), d3);
    m = dpp_min1<0x111>(m); // row_shr:1
    m = dpp_min1<0x112>(m); // row_shr:2
    m = dpp_min1<0x114>(m); // row_shr:4
    m = dpp_min1<0x118>(m); // row_shr:8
    unsigned r0 = (unsigned)__builtin_amdgcn_readlane(__float_as_int(m), 15);
    unsigned r1 = (unsigned)__builtin_amdgcn_readlane(__float_as_int(m), 31);
    unsigned r2 = (unsigned)__builtin_amdgcn_readlane(__float_as_int(m), 47);
    unsigned r3 = (unsigned)__builtin_amdgcn_readlane(__float_as_int(m), 63);
    // scalar-pipe min tree: non-negative fp32 bits sort as uint, NaN > inf
    unsigned mu = umin2(umin2(r0, r1), umin2(r2, r3));
    float mf = __uint_as_float(mu);

    // exact first-min-wins argmin, slot-major priority, all on SALU:
    // u_s = (s<<6)|ctz(e_s); empty ballot -> 0xffffffff loses the uint-min
    ull e0 = __ballot(d0 == mf);
    ull e1 = __ballot(d1 == mf);
    ull e2 = __ballot(d2 == mf);
    ull e3 = __ballot(d3 == mf);
    unsigned u0 = (unsigned)(__ffsll((long long)e0) - 1);
    unsigned u1 = (unsigned)((__ffsll((long long)e1) - 1) | 64);
    unsigned u2 = (unsigned)((__ffsll((long long)e2) - 1) | 128);
    unsigned u3 = (unsigned)((__ffsll((long long)e3) - 1) | 192);
    unsigned k  = umin2(umin2(u0, u1), umin2(u2, u3));

    // faithful to reference: se = min(m, BIG); if !(m < BIG), k = 0
    bool ok = (mu < BIG_U);          // uint compare == float compare (m >= 0)
    k  = ok ? k : 0u;                // s_cselect
    mu = umin2(mu, BIG_U);           // s_min_u32
    acc += __uint_as_float(mu);      // v_add_f32, uniform across lanes

    // poison candidate k's x-coordinate with NaN
    const float NANF = __int_as_float(0x7fc00000);
    const unsigned ks = k >> 6, kl = k & 63u;
    const bool hit = ((unsigned)lane == kl);
    p0.x = (hit && ks == 0) ? NANF : p0.x;
    p1.x = (hit && ks == 1) ? NANF : p1.x;
    p2.x = (hit && ks == 2) ? NANF : p2.x;
    p3.x = (hit && ks == 3) ? NANF : p3.x;
}

// 64 targets whose coords live in (txc,tyc) lane-slots; readlane needs a
// statically-chosen source register, hence one phase per 64-target chunk.
__device__ __forceinline__ void greedy_phase(
    float txc, float tyc, int lane, float& acc,
    v2f& p0, v2f& p1, v2f& p2, v2f& p3)
{
    #pragma unroll 1
    for (int j2 = 0; j2 < 64; ++j2) {
        float tjx = __int_as_float(__builtin_amdgcn_readlane(__float_as_int(txc), j2));
        float tjy = __int_as_float(__builtin_amdgcn_readlane(__float_as_int(tyc), j2));
        round_one(tjx, tjy, lane, acc, p0, p1, p2, p3);
    }
}

// One wave per batch; 4 waves (4 batches) per 256-thread block.
__global__ __launch_bounds__(256) void greedy_match_kernel(
    const float* __restrict__ input,
    const float* __restrict__ targets,
    float* __restrict__ out,
    int B, float scale)
{
    __shared__ float wsum[4];
    const int lane = threadIdx.x & 63;
    const int wid  = threadIdx.x >> 6;
    const int b    = blockIdx.x * 4 + wid;

    float acc = 0.0f;
    if (b < B) {
        const v2f* pin = (const v2f*)(input   + (size_t)b * (2 * N_PTS));
        const v2f* ptg = (const v2f*)(targets + (size_t)b * (2 * N_PTS));

        v2f p0 = pin[lane];
        v2f p1 = pin[64 + lane];
        v2f p2 = pin[128 + lane];
        v2f p3 = pin[192 + lane];
        v2f t0 = ptg[lane];
        v2f t1 = ptg[64 + lane];
        v2f t2 = ptg[128 + lane];
        v2f t3 = ptg[192 + lane];

        greedy_phase(t0.x, t0.y, lane, acc, p0, p1, p2, p3);
        greedy_phase(t1.x, t1.y, lane, acc, p0, p1, p2, p3);
        greedy_phase(t2.x, t2.y, lane, acc, p0, p1, p2, p3);
        greedy_phase(t3.x, t3.y, lane, acc, p0, p1, p2, p3);
    }

    if (lane == 0) wsum[wid] = acc;
    __syncthreads();
    if (threadIdx.x == 0) {
        float s = (wsum[0] + wsum[1] + wsum[2] + wsum[3]) * scale;
        atomicAdd(out, s);
    }
}

extern "C" void kernel_launch(void* const* d_in, const int* in_sizes, int n_in,
                              void* d_out, int out_size, void* d_ws, size_t ws_size,
                              hipStream_t stream) {
    const float* input   = (const float*)d_in[0];
    const float* targets = (const float*)d_in[1];
    float* out = (float*)d_out;

    const int B = in_sizes[0] / (2 * N_PTS);
    const float scale = 1.0f / ((float)B * (float)(2 * N_PTS));

    // d_out is poisoned 0xAA before every call — zero it (graph-capturable).
    hipMemsetAsync(d_out, 0, sizeof(float) * (size_t)out_size, stream);

    const int blocks = (B + 3) / 4;
    greedy_match_kernel<<<blocks, 256, 0, stream>>>(input, targets, out, B, scale);
}